// Round 4
// baseline (130.810 us; speedup 1.0000x reference)
//
#include <hip/hip_runtime.h>
#include <hip/hip_bf16.h>

// Problem constants
#define BATCH 2
#define GRP   2
#define NBG   4            // BATCH*GRP
#define CINCH 192          // input channels
#define OG    192          // output channels per group
#define HWDIM 48
#define LPIX  2304         // 48*48
#define KTAP  25           // 5x5
#define IDIM  4800         // CINCH*KTAP
#define NCHUNK 150         // IDIM/32
#define NSLICE 15          // K-split: 5 kernel rows x 3 thirds (10 chunks each)
#define XPAD  24576        // 128 l-rows * 192 c of padding each side of g_xt
#define OUTEL (NBG * OG * LPIX)   // 1769472

typedef __attribute__((ext_vector_type(4))) float  float4v;
typedef __attribute__((ext_vector_type(8))) short  short8;

// Static device scratch
// A, fragment-major: [bg][t][ot(3)][i(4)][m(16)][q(4)][e(8)] bf16
__device__ __align__(16) unsigned short g_wa[(size_t)NBG * NCHUNK * 6144];
__device__ __align__(16) unsigned short g_xt[XPAD + BATCH * LPIX * CINCH + XPAD]; // [b][l][c] bf16, padded
__device__ unsigned long long g_m64[NBG * LPIX];   // 50 mask bits per (bg,l)
__device__ __align__(16) unsigned short g_part[(size_t)NSLICE * OUTEL];  // bf16 K-split partials

__device__ __forceinline__ unsigned short f2bf(float f) {
  union { float f; unsigned int u; } un; un.f = f;
  unsigned int u = un.u;
  return (unsigned short)((u + 0x7fffu + ((u >> 16) & 1u)) >> 16);  // RNE
}

// ---------------------------------------------------------------------------
// ONE prep dispatch, block ranges:
//  [0,216)      transpose+cvt x -> g_xt
//  [216,984)    reorder dkw -> g_wa (fragment-major, coalesced 64B stores)
//  [984,1176)   mask bits -> g_m64
//  [1176,1200)  zero g_xt pads
__global__ __launch_bounds__(256) void prep(
    const float* __restrict__ x, const int* __restrict__ tg,
    const float* __restrict__ dkw) {
  __shared__ __align__(16) unsigned char smem[19200];
  const int bx = blockIdx.x, tid = threadIdx.x;

  if (bx < 216) {  // ---- transpose: 64c x 64l tiles via LDS (stride 68)
    unsigned short* tile = (unsigned short*)smem;
    const int c0 = (bx % 3) * 64;
    const int l0 = ((bx / 3) % 36) * 64;
    const int b  = bx / 108;
    #pragma unroll
    for (int it = 0; it < 4; ++it) {
      const int idx = it * 256 + tid;
      const int cl = idx >> 4, lq = idx & 15;
      const float4 v = reinterpret_cast<const float4*>(
          x + ((size_t)b * CINCH + c0 + cl) * LPIX + l0)[lq];
      unsigned short* tp = &tile[cl * 68 + lq * 4];
      tp[0] = f2bf(v.x); tp[1] = f2bf(v.y); tp[2] = f2bf(v.z); tp[3] = f2bf(v.w);
    }
    __syncthreads();
    unsigned short* dst = g_xt + XPAD + ((size_t)b * LPIX) * CINCH;
    #pragma unroll
    for (int it = 0; it < 2; ++it) {
      const int idx = it * 256 + tid;
      const int c8 = idx & 7, ll = idx >> 3;
      unsigned short pk[8];
      #pragma unroll
      for (int e = 0; e < 8; ++e) pk[e] = tile[(c8 * 8 + e) * 68 + ll];
      *reinterpret_cast<uint4*>(dst + (size_t)(l0 + ll) * CINCH + c0 + c8 * 8) =
          *reinterpret_cast<const uint4*>(pk);
    }
  } else if (bx < 984) {  // ---- weight reorder, fragment-major
    float* row = (float*)smem;                 // 4800 floats
    const int blk = bx - 216;                  // bg*192 + o
    const int bg = blk / OG, o = blk % OG;
    const float* src = dkw + (size_t)blk * IDIM;
    for (int i = tid; i < IDIM / 4; i += 256)
      reinterpret_cast<float4*>(row)[i] = reinterpret_cast<const float4*>(src)[i];
    __syncthreads();
    const int ot = o >> 6, fi = (o >> 4) & 3, m = o & 15;
    unsigned short* wbase =
        g_wa + (size_t)bg * NCHUNK * 6144 + ot * 2048 + fi * 512 + m * 32;
    for (int t = tid; t < NCHUNK; t += 256) {  // one 64B granule per t
      const int kk = t / 6, c0 = (t % 6) * 32;
      unsigned int pk[16];
      #pragma unroll
      for (int q = 0; q < 4; ++q)
        #pragma unroll
        for (int e = 0; e < 4; ++e) {
          const int c = c0 + q * 8 + e * 2;
          const unsigned lo = f2bf(row[c * KTAP + kk]);
          const unsigned hi = f2bf(row[(c + 1) * KTAP + kk]);
          pk[q * 4 + e] = lo | (hi << 16);
        }
      unsigned short* dst = wbase + (size_t)t * 6144;
      #pragma unroll
      for (int q = 0; q < 4; ++q)
        reinterpret_cast<uint4*>(dst)[q] = *reinterpret_cast<const uint4*>(pk + q * 4);
    }
  } else if (bx < 1176) {  // ---- mask bits
    const int blk = bx - 984;                  // bg*48 + h
    const int bg = blk / HWDIM, h = blk % HWDIM;
    const int b = bg >> 1, g = bg & 1;
    int* tgs = (int*)smem;                     // [2][5][48]
    for (int i = tid; i < 480; i += 256) {
      const int g2 = i / 240, r5 = (i / 48) % 5, w = i % 48;
      const int hh = h + r5 - 2;
      tgs[i] = (hh >= 0 && hh < HWDIM)
                   ? tg[((b * GRP + g2) * HWDIM + hh) * HWDIM + w]
                   : 0x7fffffff;
    }
    __syncthreads();
    if (tid < HWDIM) {
      const int w = tid;
      const int center = tgs[g * 240 + 96 + w];
      unsigned long long bits = 0ull;
      #pragma unroll
      for (int g2 = 0; g2 < GRP; ++g2)
        #pragma unroll
        for (int kk = 0; kk < KTAP; ++kk) {
          const int ww = w + kk % 5 - 2;
          if (ww >= 0 && ww < HWDIM && tgs[g2 * 240 + (kk / 5) * 48 + ww] < center)
            bits |= 1ull << (g2 * KTAP + kk);
        }
      g_m64[bg * LPIX + h * HWDIM + w] = bits;
    }
  } else {  // ---- zero g_xt pads (2 x 48 KiB)
    const int idx = (bx - 1176) * 256 + tid;   // 0..6143, 16B each
    uint4 z; z.x = z.y = z.z = z.w = 0u;
    if (idx < 3072)
      reinterpret_cast<uint4*>(g_xt)[idx] = z;
    else
      reinterpret_cast<uint4*>(g_xt + XPAD + (size_t)BATCH * LPIX * CINCH)[idx - 3072] = z;
  }
}

// ---------------------------------------------------------------------------
// GEMM (R15): zero-LDS structure from R12, latency hidden by TLP instead of
// ILP. R12/R13 counters (MfmaUtil 13.8, VALU 8.7, HBM 8%, LDS 0) = pure
// latency-bound at 2.1 waves/SIMD; the compiler collapses source-level deep
// pipelines (R13: VGPR 68) and the asm-pinned variant didn't survive the
// harness (R14). Fix the wave supply instead: split each kernel row's 30
// chunks into 3 thirds of 10 -> 15 K-slices, grid 3240 blocks = 6480 waves
// = 6.3 waves/SIMD (VGPR ~76 allows 6). Per-wave structure identical to
// R12: 1-deep register double-buffer, masked B taps redirected to the
// zeroed pad, 4x4 16x16x32 MFMA per chunk, bf16 partial stores (now 15
// slices). Swizzle bijective: 3240 = 8*405.
__global__ __launch_bounds__(128, 4) void gemm_masked() {
  const int n = blockIdx.x;                  // 0..3239
  const int m = ((n & 7) * 405) + (n >> 3);  // XCD-contiguous work id
  const int ltile = m % 18;                  // l-tile of 128
  const int s  = m / 18;                     // 0..179 = (otile,bg,slice)
  const int otile = s % 3;
  const int zz = s / 3;                      // 0..59
  const int bg = zz & 3;
  const int slice = zz >> 2;                 // 0..14
  const int ks = slice / 3;                  // kernel row 0..4
  const int t0 = (slice % 3) * 10;           // local chunk range [t0, t0+10)
  const int b  = bg >> 1;
  const int lbase = ltile * 128, obase = otile * 64;
  const int tid = threadIdx.x, lane = tid & 63, wv = tid >> 6;
  const int q = lane >> 4, m16 = lane & 15;

  // A fragment source: local chunk lt at abase + lt*6144 (shorts), frag i*512
  const unsigned short* abase =
      g_wa + ((size_t)bg * NCHUNK + ks * 30) * 6144 + otile * 2048 + m16 * 32 + q * 8;

  // per-fragment masks (pre-shifted by ks*5) and per-j B row pointers
  unsigned bls[4], bhs[4];
  const unsigned short* brow[4];
  const int wl0 = lbase + (ks - 2) * HWDIM - 2;   // window row 0 in l-space
  #pragma unroll
  for (int j = 0; j < 4; ++j) {
    const int lj = wv * 64 + j * 16 + m16;
    const unsigned long long bits = g_m64[bg * LPIX + lbase + lj];
    bls[j] = ((unsigned)(bits & 0x1ffffffull)) >> (ks * 5);
    bhs[j] = ((unsigned)((bits >> KTAP) & 0x1ffffffull)) >> (ks * 5);
    brow[j] = g_xt + XPAD + (ptrdiff_t)((ptrdiff_t)b * LPIX + wl0 + lj) * CINCH + q * 8;
  }
  const unsigned short* zptr = g_xt + q * 8;      // zeroed leading pad

  short8 Af[2][4], Bf[2][4];

#define LOADA(lt, sl)                                                       \
  {                                                                         \
    const unsigned short* _as = abase + (size_t)(lt) * 6144;                \
    _Pragma("unroll")                                                       \
    for (int i = 0; i < 4; ++i)                                             \
      Af[sl][i] = *reinterpret_cast<const short8*>(_as + i * 512);          \
  }
#define LOADB(lt, sl)                                                       \
  {                                                                         \
    const int _kt = (lt) / 6, _ci = (lt) % 6;                               \
    _Pragma("unroll")                                                       \
    for (int j = 0; j < 4; ++j) {                                           \
      const unsigned bit = (((_ci >= 3) ? bhs[j] : bls[j]) >> _kt) & 1u;    \
      const unsigned short* _p =                                            \
          bit ? (brow[j] + _kt * CINCH + _ci * 32) : zptr;                  \
      Bf[sl][j] = *reinterpret_cast<const short8*>(_p);                     \
    }                                                                       \
  }

  float4v acc[4][4];
  #pragma unroll
  for (int i = 0; i < 4; ++i)
    #pragma unroll
    for (int j = 0; j < 4; ++j) acc[i][j] = (float4v)(0.0f);

  LOADA(t0, 0) LOADB(t0, 0)
  #pragma unroll
  for (int k = 0; k < 10; ++k) {     // fully unrolled: slot indices static
    const int cur = k & 1, nxt = cur ^ 1;
    if (k < 9) { LOADA(t0 + k + 1, nxt) LOADB(t0 + k + 1, nxt) }
    #pragma unroll
    for (int i = 0; i < 4; ++i)
      #pragma unroll
      for (int j = 0; j < 4; ++j)
        acc[i][j] = __builtin_amdgcn_mfma_f32_16x16x32_bf16(Af[cur][i], Bf[cur][j],
                                                            acc[i][j], 0, 0, 0);
  }
#undef LOADA
#undef LOADB

  // Epilogue: bf16 partial stores to g_part[slice][bg][o][l].
  // C/D layout: col = lane&15, row = q*4 + r.
  unsigned short* pb = g_part + (size_t)slice * OUTEL + (size_t)bg * OG * LPIX;
  #pragma unroll
  for (int i = 0; i < 4; ++i) {
    const int og = obase + i * 16 + q * 4;
    #pragma unroll
    for (int j = 0; j < 4; ++j) {
      const int cl = lbase + wv * 64 + j * 16 + m16;
      #pragma unroll
      for (int r = 0; r < 4; ++r)
        pb[(size_t)(og + r) * LPIX + cl] = f2bf(acc[i][j][r]);
    }
  }
}

// ---------------------------------------------------------------------------
// Reduce: out = sum_slice bf16(g_part[slice]) + bias. 8 elements per thread.
__global__ __launch_bounds__(256) void reduce_part(
    const float* __restrict__ dkb, float* __restrict__ out) {
  const int t8 = blockIdx.x * 256 + threadIdx.x;   // 0..221183
  const size_t e0 = (size_t)t8 * 8;
  const int row = (int)(e0 / LPIX);                // bg*192 + o (8 els same row)
  const float bias = dkb[row];
  float s[8];
  #pragma unroll
  for (int k = 0; k < 8; ++k) s[k] = bias;
  #pragma unroll
  for (int ks = 0; ks < NSLICE; ++ks) {
    const uint4 v = *reinterpret_cast<const uint4*>(
        g_part + (size_t)ks * OUTEL + e0);
    const unsigned u[4] = {v.x, v.y, v.z, v.w};
    #pragma unroll
    for (int p = 0; p < 4; ++p) {
      union { unsigned u; float f; } lo, hi;
      lo.u = u[p] << 16;
      hi.u = u[p] & 0xffff0000u;
      s[2 * p]     += lo.f;
      s[2 * p + 1] += hi.f;
    }
  }
  float4 o0, o1;
  o0.x = s[0]; o0.y = s[1]; o0.z = s[2]; o0.w = s[3];
  o1.x = s[4]; o1.y = s[5]; o1.z = s[6]; o1.w = s[7];
  reinterpret_cast<float4*>(out)[t8 * 2]     = o0;
  reinterpret_cast<float4*>(out)[t8 * 2 + 1] = o1;
}

// ---------------------------------------------------------------------------
extern "C" void kernel_launch(void* const* d_in, const int* in_sizes, int n_in,
                              void* d_out, int out_size, void* d_ws, size_t ws_size,
                              hipStream_t stream) {
  const float* x   = (const float*)d_in[0];
  const int*   tg  = (const int*)d_in[1];
  const float* dkw = (const float*)d_in[2];
  const float* dkb = (const float*)d_in[3];
  float* out = (float*)d_out;

  prep<<<dim3(1200), 256, 0, stream>>>(x, tg, dkw);
  gemm_masked<<<dim3(3240), 128, 0, stream>>>();
  reduce_part<<<dim3(OUTEL / 2048), 256, 0, stream>>>(dkb, out);
}

// Round 5
// 129.964 us; speedup vs baseline: 1.0065x; 1.0065x over previous
//
#include <hip/hip_runtime.h>
#include <hip/hip_bf16.h>

// Problem constants
#define BATCH 2
#define GRP   2
#define NBG   4            // BATCH*GRP
#define CINCH 192          // input channels
#define OG    192          // output channels per group
#define HWDIM 48
#define LPIX  2304         // 48*48
#define KTAP  25           // 5x5
#define IDIM  4800         // CINCH*KTAP
#define NCHUNK 150         // IDIM/32
#define KSPLIT 5           // one kernel row (5 taps) per split
#define XPAD  24576        // 128 l-rows * 192 c of padding each side of g_xt
#define OUTEL (NBG * OG * LPIX)   // 1769472

typedef __attribute__((ext_vector_type(4))) float  float4v;
typedef __attribute__((ext_vector_type(8))) short  short8;

// Static device scratch
// A, fragment-major: [bg][t][ot(3)][i(4)][m(16)][q(4)][e(8)] bf16
__device__ __align__(16) unsigned short g_wa[(size_t)NBG * NCHUNK * 6144];
__device__ __align__(16) unsigned short g_xt[XPAD + BATCH * LPIX * CINCH + XPAD]; // [b][l][c] bf16, padded
__device__ unsigned long long g_m64[NBG * LPIX];   // 50 mask bits per (bg,l)
__device__ __align__(16) unsigned short g_part[(size_t)KSPLIT * OUTEL];  // bf16 K-split partials

__device__ __forceinline__ unsigned short f2bf(float f) {
  union { float f; unsigned int u; } un; un.f = f;
  unsigned int u = un.u;
  return (unsigned short)((u + 0x7fffu + ((u >> 16) & 1u)) >> 16);  // RNE
}

// ---------------------------------------------------------------------------
// ONE prep dispatch, block ranges:
//  [0,216)      transpose+cvt x -> g_xt
//  [216,984)    reorder dkw -> g_wa (fragment-major, coalesced 64B stores)
//  [984,1176)   mask bits -> g_m64
//  [1176,1200)  zero g_xt pads
__global__ __launch_bounds__(256) void prep(
    const float* __restrict__ x, const int* __restrict__ tg,
    const float* __restrict__ dkw) {
  __shared__ __align__(16) unsigned char smem[19200];
  const int bx = blockIdx.x, tid = threadIdx.x;

  if (bx < 216) {  // ---- transpose: 64c x 64l tiles via LDS (stride 68)
    unsigned short* tile = (unsigned short*)smem;
    const int c0 = (bx % 3) * 64;
    const int l0 = ((bx / 3) % 36) * 64;
    const int b  = bx / 108;
    #pragma unroll
    for (int it = 0; it < 4; ++it) {
      const int idx = it * 256 + tid;
      const int cl = idx >> 4, lq = idx & 15;
      const float4 v = reinterpret_cast<const float4*>(
          x + ((size_t)b * CINCH + c0 + cl) * LPIX + l0)[lq];
      unsigned short* tp = &tile[cl * 68 + lq * 4];
      tp[0] = f2bf(v.x); tp[1] = f2bf(v.y); tp[2] = f2bf(v.z); tp[3] = f2bf(v.w);
    }
    __syncthreads();
    unsigned short* dst = g_xt + XPAD + ((size_t)b * LPIX) * CINCH;
    #pragma unroll
    for (int it = 0; it < 2; ++it) {
      const int idx = it * 256 + tid;
      const int c8 = idx & 7, ll = idx >> 3;
      unsigned short pk[8];
      #pragma unroll
      for (int e = 0; e < 8; ++e) pk[e] = tile[(c8 * 8 + e) * 68 + ll];
      *reinterpret_cast<uint4*>(dst + (size_t)(l0 + ll) * CINCH + c0 + c8 * 8) =
          *reinterpret_cast<const uint4*>(pk);
    }
  } else if (bx < 984) {  // ---- weight reorder, fragment-major
    float* row = (float*)smem;                 // 4800 floats
    const int blk = bx - 216;                  // bg*192 + o
    const int bg = blk / OG, o = blk % OG;
    const float* src = dkw + (size_t)blk * IDIM;
    for (int i = tid; i < IDIM / 4; i += 256)
      reinterpret_cast<float4*>(row)[i] = reinterpret_cast<const float4*>(src)[i];
    __syncthreads();
    const int ot = o >> 6, fi = (o >> 4) & 3, m = o & 15;
    unsigned short* wbase =
        g_wa + (size_t)bg * NCHUNK * 6144 + ot * 2048 + fi * 512 + m * 32;
    for (int t = tid; t < NCHUNK; t += 256) {  // one 64B granule per t
      const int kk = t / 6, c0 = (t % 6) * 32;
      unsigned int pk[16];
      #pragma unroll
      for (int q = 0; q < 4; ++q)
        #pragma unroll
        for (int e = 0; e < 4; ++e) {
          const int c = c0 + q * 8 + e * 2;
          const unsigned lo = f2bf(row[c * KTAP + kk]);
          const unsigned hi = f2bf(row[(c + 1) * KTAP + kk]);
          pk[q * 4 + e] = lo | (hi << 16);
        }
      unsigned short* dst = wbase + (size_t)t * 6144;
      #pragma unroll
      for (int q = 0; q < 4; ++q)
        reinterpret_cast<uint4*>(dst)[q] = *reinterpret_cast<const uint4*>(pk + q * 4);
    }
  } else if (bx < 1176) {  // ---- mask bits
    const int blk = bx - 984;                  // bg*48 + h
    const int bg = blk / HWDIM, h = blk % HWDIM;
    const int b = bg >> 1, g = bg & 1;
    int* tgs = (int*)smem;                     // [2][5][48]
    for (int i = tid; i < 480; i += 256) {
      const int g2 = i / 240, r5 = (i / 48) % 5, w = i % 48;
      const int hh = h + r5 - 2;
      tgs[i] = (hh >= 0 && hh < HWDIM)
                   ? tg[((b * GRP + g2) * HWDIM + hh) * HWDIM + w]
                   : 0x7fffffff;
    }
    __syncthreads();
    if (tid < HWDIM) {
      const int w = tid;
      const int center = tgs[g * 240 + 96 + w];
      unsigned long long bits = 0ull;
      #pragma unroll
      for (int g2 = 0; g2 < GRP; ++g2)
        #pragma unroll
        for (int kk = 0; kk < KTAP; ++kk) {
          const int ww = w + kk % 5 - 2;
          if (ww >= 0 && ww < HWDIM && tgs[g2 * 240 + (kk / 5) * 48 + ww] < center)
            bits |= 1ull << (g2 * KTAP + kk);
        }
      g_m64[bg * LPIX + h * HWDIM + w] = bits;
    }
  } else {  // ---- zero g_xt pads (2 x 48 KiB)
    const int idx = (bx - 1176) * 256 + tid;   // 0..6143, 16B each
    uint4 z; z.x = z.y = z.z = z.w = 0u;
    if (idx < 3072)
      reinterpret_cast<uint4*>(g_xt)[idx] = z;
    else
      reinterpret_cast<uint4*>(g_xt + XPAD + (size_t)BATCH * LPIX * CINCH)[idx - 3072] = z;
  }
}

// ---------------------------------------------------------------------------
// GEMM (R16): zero-LDS + asm-pinned 4-deep register pipeline. The R12-R15
// evidence chain: MfmaUtil stuck ~13% and VGPR_Count 64-76 across all
// source-level variants -> hipcc collapses any source prefetch into a tiny
// register window, serializing each chunk's 8 loads as dependent
// full-latency chains (~3.6kcyc/chunk observed; TLP at 2-3.5 waves/SIMD
// can't hide 8x serialization, R15). Fix: every global_load_dwordx4 is its
// own single-output `asm volatile` ("=&v" pins a distinct dest reg; volatile
// pins issue order), 4 chunk slots, counted `s_waitcnt vmcnt(24)` before
// consuming (3 chunks = 24 loads stay in flight; never drained mid-loop) +
// sched_barrier(0) so MFMAs can't hoist above the wait (rule #18). Steady
// state from a constant-trip unrolled loop (all slot indices static).
// Budget: Af 64 + Bf 64 + acc 64 (AGPR, unified) + ~25 addr ~= 215 < 256
// -> 2 waves/SIMD (= grid supply). Config reverted to R12: grid 1080,
// 5 K-slices (kernel rows), 30 chunks/block, 17.6MB partials.
__global__ __launch_bounds__(128, 2) void gemm_masked() {
  const int n = blockIdx.x;                  // 0..1079
  const int m = ((n & 7) * 135) + (n >> 3);  // XCD-contiguous work id
  const int ltile = m % 18;                  // l-tile of 128
  const int s  = m / 18;                     // slice 0..59 = (otile,bg,ks)
  const int otile = s % 3;
  const int zz = s / 3;                      // 0..19
  const int bg = zz & 3;
  const int ks = zz >> 2;                    // kernel row 0..4
  const int b  = bg >> 1;
  const int lbase = ltile * 128, obase = otile * 64;
  const int tid = threadIdx.x, lane = tid & 63, wv = tid >> 6;
  const int q = lane >> 4, m16 = lane & 15;

  // A fragment source: chunk tt at abase + tt*6144 shorts, frag i at +i*512
  const unsigned short* abase =
      g_wa + ((size_t)bg * NCHUNK + ks * 30) * 6144 + otile * 2048 + m16 * 32 + q * 8;

  // per-fragment masks (pre-shifted by ks*5) and per-j B row pointers
  unsigned bls[4], bhs[4];
  const unsigned short* brow[4];
  const int wl0 = lbase + (ks - 2) * HWDIM - 2;   // window row 0 in l-space
  #pragma unroll
  for (int j = 0; j < 4; ++j) {
    const int lj = wv * 64 + j * 16 + m16;
    const unsigned long long bits = g_m64[bg * LPIX + lbase + lj];
    bls[j] = ((unsigned)(bits & 0x1ffffffull)) >> (ks * 5);
    bhs[j] = ((unsigned)((bits >> KTAP) & 0x1ffffffull)) >> (ks * 5);
    brow[j] = g_xt + XPAD + (ptrdiff_t)((ptrdiff_t)b * LPIX + wl0 + lj) * CINCH + q * 8;
  }
  const unsigned short* zptr = g_xt + q * 8;      // zeroed leading pad (48 KiB)

  short8 Af[4][4], Bf[4][4];

  // Issue chunk tt's 4 A-frag loads into slot sl (single-output asms)
#define ISSUE_A(tt, sl)                                                       \
  {                                                                           \
    const unsigned short* _ap = abase + (size_t)(tt) * 6144;                  \
    asm volatile("global_load_dwordx4 %0, %1, off"                            \
                 : "=&v"(Af[sl][0]) : "v"(_ap));                              \
    asm volatile("global_load_dwordx4 %0, %1, off offset:1024"                \
                 : "=&v"(Af[sl][1]) : "v"(_ap));                              \
    asm volatile("global_load_dwordx4 %0, %1, off offset:2048"                \
                 : "=&v"(Af[sl][2]) : "v"(_ap));                              \
    asm volatile("global_load_dwordx4 %0, %1, off offset:3072"                \
                 : "=&v"(Af[sl][3]) : "v"(_ap));                              \
  }
  // Issue chunk tt's 4 B-frag loads into slot sl (masked taps -> zero pad)
#define ISSUE_B(tt, sl)                                                       \
  {                                                                           \
    const int _kt = (tt) / 6, _ci = (tt) % 6;                                 \
    _Pragma("unroll")                                                         \
    for (int j = 0; j < 4; ++j) {                                             \
      const unsigned bit = (((_ci >= 3) ? bhs[j] : bls[j]) >> _kt) & 1u;      \
      const unsigned short* _p =                                              \
          (bit ? brow[j] : zptr) + _kt * CINCH + _ci * 32;                    \
      asm volatile("global_load_dwordx4 %0, %1, off"                          \
                   : "=&v"(Bf[sl][j]) : "v"(_p));                             \
    }                                                                         \
  }
#define WAITV(nn)                                                             \
  asm volatile("s_waitcnt vmcnt(" #nn ")" ::: "memory");                      \
  __builtin_amdgcn_sched_barrier(0);
#define MFMA_STEP(sl)                                                         \
  _Pragma("unroll")                                                           \
  for (int i = 0; i < 4; ++i)                                                 \
    _Pragma("unroll")                                                         \
    for (int j = 0; j < 4; ++j)                                               \
      acc[i][j] = __builtin_amdgcn_mfma_f32_16x16x32_bf16(                    \
          Af[sl][i], Bf[sl][j], acc[i][j], 0, 0, 0);

  float4v acc[4][4];
  #pragma unroll
  for (int i = 0; i < 4; ++i)
    #pragma unroll
    for (int j = 0; j < 4; ++j) acc[i][j] = (float4v)(0.0f);

  // ---- prologue: fill 3 chunks (24 loads in flight)
  ISSUE_A(0, 0) ISSUE_B(0, 0)
  ISSUE_A(1, 1) ISSUE_B(1, 1)
  ISSUE_A(2, 2) ISSUE_B(2, 2)

  // ---- steady state: issue chunk tt+3, wait chunk tt landed, compute it
  #pragma unroll
  for (int tt = 0; tt < 27; ++tt) {
    ISSUE_A(tt + 3, (tt + 3) & 3)
    ISSUE_B(tt + 3, (tt + 3) & 3)
    WAITV(24)
    MFMA_STEP(tt & 3)
  }
  // ---- tail: chunks 27,28,29 live in slots 3,0,1
  WAITV(16) MFMA_STEP(3)
  WAITV(8)  MFMA_STEP(0)
  WAITV(0)  MFMA_STEP(1)

#undef MFMA_STEP
#undef WAITV
#undef ISSUE_B
#undef ISSUE_A

  // Epilogue: bf16 partial stores to g_part[ks][bg][o][l].
  // C/D layout: col = lane&15, row = q*4 + r.
  unsigned short* pb = g_part + (size_t)ks * OUTEL + (size_t)bg * OG * LPIX;
  #pragma unroll
  for (int i = 0; i < 4; ++i) {
    const int og = obase + i * 16 + q * 4;
    #pragma unroll
    for (int j = 0; j < 4; ++j) {
      const int cl = lbase + wv * 64 + j * 16 + m16;
      #pragma unroll
      for (int r = 0; r < 4; ++r)
        pb[(size_t)(og + r) * LPIX + cl] = f2bf(acc[i][j][r]);
    }
  }
}

// ---------------------------------------------------------------------------
// Reduce: out = sum_ks bf16(g_part[ks]) + bias. 8 elements per thread.
__global__ __launch_bounds__(256) void reduce_part(
    const float* __restrict__ dkb, float* __restrict__ out) {
  const int t8 = blockIdx.x * 256 + threadIdx.x;   // 0..221183
  const size_t e0 = (size_t)t8 * 8;
  const int row = (int)(e0 / LPIX);                // bg*192 + o (8 els same row)
  const float bias = dkb[row];
  float s[8];
  #pragma unroll
  for (int k = 0; k < 8; ++k) s[k] = bias;
  #pragma unroll
  for (int ks = 0; ks < KSPLIT; ++ks) {
    const uint4 v = *reinterpret_cast<const uint4*>(
        g_part + (size_t)ks * OUTEL + e0);
    const unsigned u[4] = {v.x, v.y, v.z, v.w};
    #pragma unroll
    for (int p = 0; p < 4; ++p) {
      union { unsigned u; float f; } lo, hi;
      lo.u = u[p] << 16;
      hi.u = u[p] & 0xffff0000u;
      s[2 * p]     += lo.f;
      s[2 * p + 1] += hi.f;
    }
  }
  float4 o0, o1;
  o0.x = s[0]; o0.y = s[1]; o0.z = s[2]; o0.w = s[3];
  o1.x = s[4]; o1.y = s[5]; o1.z = s[6]; o1.w = s[7];
  reinterpret_cast<float4*>(out)[t8 * 2]     = o0;
  reinterpret_cast<float4*>(out)[t8 * 2 + 1] = o1;
}

// ---------------------------------------------------------------------------
extern "C" void kernel_launch(void* const* d_in, const int* in_sizes, int n_in,
                              void* d_out, int out_size, void* d_ws, size_t ws_size,
                              hipStream_t stream) {
  const float* x   = (const float*)d_in[0];
  const int*   tg  = (const int*)d_in[1];
  const float* dkw = (const float*)d_in[2];
  const float* dkb = (const float*)d_in[3];
  float* out = (float*)d_out;

  prep<<<dim3(1200), 256, 0, stream>>>(x, tg, dkw);
  gemm_masked<<<dim3(1080), 128, 0, stream>>>();
  reduce_part<<<dim3(OUTEL / 2048), 256, 0, stream>>>(dkb, out);
}

// Round 6
// 107.506 us; speedup vs baseline: 1.2168x; 1.2089x over previous
//
#include <hip/hip_runtime.h>
#include <hip/hip_bf16.h>

// Problem constants
#define BATCH 2
#define GRP   2
#define NBG   4            // BATCH*GRP
#define CINCH 192          // input channels
#define OG    192          // output channels per group
#define HWDIM 48
#define LPIX  2304         // 48*48
#define KTAP  25           // 5x5
#define IDIM  4800         // CINCH*KTAP
#define NCHUNK 150         // IDIM/32
#define KSPLIT 5           // one kernel row (5 taps) per split
#define XPAD  24576        // 128 l-rows * 192 c of padding each side of g_xt
#define OUTEL (NBG * OG * LPIX)   // 1769472
#define LROW  400          // LDS bytes per staged B row (384 data + 16 pad)
#define ZOFF  (132 * LROW) // zero line offset (52800)
#define AOFF  (ZOFF + 64)  // A double-buffer offset; LDS total = AOFF + 16384

typedef __attribute__((ext_vector_type(4))) float  float4v;
typedef __attribute__((ext_vector_type(8))) short  short8;

// Static device scratch
// A, fragment-major: [bg][t][ot(3)][i(4)][m(16)][q(4)][e(8)] bf16
__device__ __align__(16) unsigned short g_wa[(size_t)NBG * NCHUNK * 6144];
__device__ __align__(16) unsigned short g_xt[XPAD + BATCH * LPIX * CINCH + XPAD]; // [b][l][c] bf16, padded
__device__ unsigned long long g_m64[NBG * LPIX];   // 50 mask bits per (bg,l)
__device__ __align__(16) unsigned short g_part[(size_t)KSPLIT * OUTEL];  // bf16 K-split partials

__device__ __forceinline__ unsigned short f2bf(float f) {
  union { float f; unsigned int u; } un; un.f = f;
  unsigned int u = un.u;
  return (unsigned short)((u + 0x7fffu + ((u >> 16) & 1u)) >> 16);  // RNE
}

// ---------------------------------------------------------------------------
// ONE prep dispatch, block ranges:
//  [0,216)      transpose+cvt x -> g_xt
//  [216,984)    reorder dkw -> g_wa (fragment-major, coalesced 64B stores)
//  [984,1176)   mask bits -> g_m64
//  [1176,1200)  zero g_xt pads
__global__ __launch_bounds__(256) void prep(
    const float* __restrict__ x, const int* __restrict__ tg,
    const float* __restrict__ dkw) {
  __shared__ __align__(16) unsigned char smem[19200];
  const int bx = blockIdx.x, tid = threadIdx.x;

  if (bx < 216) {  // ---- transpose: 64c x 64l tiles via LDS (stride 68)
    unsigned short* tile = (unsigned short*)smem;
    const int c0 = (bx % 3) * 64;
    const int l0 = ((bx / 3) % 36) * 64;
    const int b  = bx / 108;
    #pragma unroll
    for (int it = 0; it < 4; ++it) {
      const int idx = it * 256 + tid;
      const int cl = idx >> 4, lq = idx & 15;
      const float4 v = reinterpret_cast<const float4*>(
          x + ((size_t)b * CINCH + c0 + cl) * LPIX + l0)[lq];
      unsigned short* tp = &tile[cl * 68 + lq * 4];
      tp[0] = f2bf(v.x); tp[1] = f2bf(v.y); tp[2] = f2bf(v.z); tp[3] = f2bf(v.w);
    }
    __syncthreads();
    unsigned short* dst = g_xt + XPAD + ((size_t)b * LPIX) * CINCH;
    #pragma unroll
    for (int it = 0; it < 2; ++it) {
      const int idx = it * 256 + tid;
      const int c8 = idx & 7, ll = idx >> 3;
      unsigned short pk[8];
      #pragma unroll
      for (int e = 0; e < 8; ++e) pk[e] = tile[(c8 * 8 + e) * 68 + ll];
      *reinterpret_cast<uint4*>(dst + (size_t)(l0 + ll) * CINCH + c0 + c8 * 8) =
          *reinterpret_cast<const uint4*>(pk);
    }
  } else if (bx < 984) {  // ---- weight reorder, fragment-major
    float* row = (float*)smem;                 // 4800 floats
    const int blk = bx - 216;                  // bg*192 + o
    const int bg = blk / OG, o = blk % OG;
    const float* src = dkw + (size_t)blk * IDIM;
    for (int i = tid; i < IDIM / 4; i += 256)
      reinterpret_cast<float4*>(row)[i] = reinterpret_cast<const float4*>(src)[i];
    __syncthreads();
    const int ot = o >> 6, fi = (o >> 4) & 3, m = o & 15;
    unsigned short* wbase =
        g_wa + (size_t)bg * NCHUNK * 6144 + ot * 2048 + fi * 512 + m * 32;
    for (int t = tid; t < NCHUNK; t += 256) {  // one 64B granule per t
      const int kk = t / 6, c0 = (t % 6) * 32;
      unsigned int pk[16];
      #pragma unroll
      for (int q = 0; q < 4; ++q)
        #pragma unroll
        for (int e = 0; e < 4; ++e) {
          const int c = c0 + q * 8 + e * 2;
          const unsigned lo = f2bf(row[c * KTAP + kk]);
          const unsigned hi = f2bf(row[(c + 1) * KTAP + kk]);
          pk[q * 4 + e] = lo | (hi << 16);
        }
      unsigned short* dst = wbase + (size_t)t * 6144;
      #pragma unroll
      for (int q = 0; q < 4; ++q)
        reinterpret_cast<uint4*>(dst)[q] = *reinterpret_cast<const uint4*>(pk + q * 4);
    }
  } else if (bx < 1176) {  // ---- mask bits
    const int blk = bx - 984;                  // bg*48 + h
    const int bg = blk / HWDIM, h = blk % HWDIM;
    const int b = bg >> 1, g = bg & 1;
    int* tgs = (int*)smem;                     // [2][5][48]
    for (int i = tid; i < 480; i += 256) {
      const int g2 = i / 240, r5 = (i / 48) % 5, w = i % 48;
      const int hh = h + r5 - 2;
      tgs[i] = (hh >= 0 && hh < HWDIM)
                   ? tg[((b * GRP + g2) * HWDIM + hh) * HWDIM + w]
                   : 0x7fffffff;
    }
    __syncthreads();
    if (tid < HWDIM) {
      const int w = tid;
      const int center = tgs[g * 240 + 96 + w];
      unsigned long long bits = 0ull;
      #pragma unroll
      for (int g2 = 0; g2 < GRP; ++g2)
        #pragma unroll
        for (int kk = 0; kk < KTAP; ++kk) {
          const int ww = w + kk % 5 - 2;
          if (ww >= 0 && ww < HWDIM && tgs[g2 * 240 + (kk / 5) * 48 + ww] < center)
            bits |= 1ull << (g2 * KTAP + kk);
        }
      g_m64[bg * LPIX + h * HWDIM + w] = bits;
    }
  } else {  // ---- zero g_xt pads (2 x 48 KiB)
    const int idx = (bx - 1176) * 256 + tid;   // 0..6143, 16B each
    uint4 z; z.x = z.y = z.z = z.w = 0u;
    if (idx < 3072)
      reinterpret_cast<uint4*>(g_xt)[idx] = z;
    else
      reinterpret_cast<uint4*>(g_xt + XPAD + (size_t)BATCH * LPIX * CINCH)[idx - 3072] = z;
  }
}

// ---------------------------------------------------------------------------
// GEMM (R17): return to the R11 LDS design (best measured: <=43.6us gemm,
// 113us total vs 121-131 for every zero-LDS variant R12-R16), fixing its two
// real defects:
//  (1) 1 wave/SIMD -> now 256-thread block (4 waves), same o64 x l128 tile;
//      each wave owns l32 (2 j-frags, acc[4][2]). 2 blocks/CU x 4 waves =
//      2 waves/SIMD: while one block drains its pair barrier, the other
//      block's waves compute (m114 implicit overlap).
//  (2) A staged via VGPR round-trip -> now global_load_lds(16B) async DMA.
//      The A chunk slab is linear in tid*16 bytes, exactly the wave-uniform
//      base + lane*16 layout the DMA requires. Staging for pair pt+1 is
//      issued BEFORE pair pt's compute; __syncthreads() drains it at the
//      pair boundary (minimum 2-phase pipeline, T3 recipe).
// B window (132 rows x 400B padded, bank-conflict-free), zero line for
// masked taps, mask bits, epilogue unchanged from R11.
__global__ __launch_bounds__(256, 2) void gemm_masked() {
  __shared__ __align__(16) unsigned char sB[AOFF + 16384];

  const int n = blockIdx.x;                  // 0..1079
  const int m = ((n & 7) * 135) + (n >> 3);  // XCD-contiguous work id
  const int ltile = m % 18;                  // l-tile of 128
  const int s  = m / 18;                     // slice 0..59 = (otile,bg,ks)
  const int otile = s % 3;
  const int zz = s / 3;                      // 0..19
  const int bg = zz & 3;
  const int ks = zz >> 2;                    // kernel row 0..4
  const int b  = bg >> 1;
  const int lbase = ltile * 128, obase = otile * 64;
  const int tid = threadIdx.x, lane = tid & 63, wv = tid >> 6;
  const int q = lane >> 4, m16 = lane & 15;

  // per-thread A source: granule tid (16B) of chunk t's 4KB otile slab
  const unsigned short* aslab =
      g_wa + ((size_t)bg * NCHUNK + ks * 30) * 6144 + otile * 2048 + tid * 8;

  // async 16B global->LDS; lds side = wave-uniform base + lane*16
#define GLL(gsrc, ldsoff)                                                     \
  __builtin_amdgcn_global_load_lds(                                           \
      (const __attribute__((address_space(1))) void*)(gsrc),                  \
      (__attribute__((address_space(3))) void*)(sB + (ldsoff)), 16, 0, 0);

  // ---- prologue: issue A pair 0 into buf 0 (chunks 0,1)
  GLL(aslab,        AOFF + 0 * 4096 + wv * 1024)
  GLL(aslab + 6144, AOFF + 1 * 4096 + wv * 1024)

  // ---- stage window rows [wl0, wl0+131] (contiguous in g_xt) into LDS
  const int wl0 = lbase + (ks - 2) * HWDIM - 2;
  const unsigned short* xwin = g_xt + XPAD + (ptrdiff_t)(b * LPIX + wl0) * CINCH;
  #pragma unroll
  for (int it = 0; it < 13; ++it) {          // 132*24 = 3168 granules of 16 B
    const int i = it * 256 + tid;
    if (it < 12 || i < 3168) {
      const int r = i / 24, g = i % 24;      // src is linear: granule i
      *reinterpret_cast<uint4*>(sB + r * LROW + g * 16) =
          *reinterpret_cast<const uint4*>(xwin + i * 8);
    }
  }
  if (tid < 4) {  // zero line
    uint4 z; z.x = z.y = z.z = z.w = 0u;
    *reinterpret_cast<uint4*>(sB + ZOFF + tid * 16) = z;
  }

  // ---- per-fragment masks (pre-shifted by ks*5) and LDS base offsets
  unsigned bls[2], bhs[2], bboff[2];
  #pragma unroll
  for (int jj = 0; jj < 2; ++jj) {
    const int lj = wv * 32 + jj * 16 + m16;
    const unsigned long long bits = g_m64[bg * LPIX + lbase + lj];
    bls[jj] = ((unsigned)(bits & 0x1ffffffull)) >> (ks * 5);
    bhs[jj] = ((unsigned)((bits >> KTAP) & 0x1ffffffull)) >> (ks * 5);
    bboff[jj] = lj * LROW + q * 16;
  }
  const unsigned zoff = ZOFF + q * 16;

#define LOADB(tt, Bf)                                                       \
  {                                                                         \
    const int _kt = (tt) / 6, _ci = (tt) % 6;                               \
    _Pragma("unroll")                                                       \
    for (int jj = 0; jj < 2; ++jj) {                                        \
      const unsigned bit = (((_ci >= 3) ? bhs[jj] : bls[jj]) >> _kt) & 1u;  \
      const unsigned off =                                                  \
          bit ? (bboff[jj] + _kt * LROW + _ci * 64) : zoff;                 \
      Bf[jj] = *reinterpret_cast<const short8*>(sB + off);                  \
    }                                                                       \
  }

  float4v acc[4][2];
  #pragma unroll
  for (int i = 0; i < 4; ++i)
    #pragma unroll
    for (int jj = 0; jj < 2; ++jj) acc[i][jj] = (float4v)(0.0f);

  __syncthreads();   // window + A pair 0 visible (vmcnt drained by barrier)

  #pragma unroll
  for (int pt = 0; pt < 15; ++pt) {
    // issue async A staging for pair pt+1 into the other buffer FIRST
    // (safe: that buffer's reads finished before the previous barrier)
    if (pt < 14) {
      const unsigned short* src = aslab + (size_t)(2 * pt + 2) * 6144;
      const int boff = AOFF + ((pt + 1) & 1) * 8192 + wv * 1024;
      GLL(src,        boff)
      GLL(src + 6144, boff + 4096)
    }
    // compute pair pt from A buffer (pt&1)
    #pragma unroll
    for (int cc = 0; cc < 2; ++cc) {
      const int tt = 2 * pt + cc;
      const unsigned char* ab = sB + AOFF + (pt & 1) * 8192 + cc * 4096;
      short8 Afr[4];
      #pragma unroll
      for (int i = 0; i < 4; ++i)
        Afr[i] = *reinterpret_cast<const short8*>(ab + i * 1024 + m16 * 64 + q * 16);
      short8 Bfr[2];
      LOADB(tt, Bfr)
      #pragma unroll
      for (int i = 0; i < 4; ++i)
        #pragma unroll
        for (int jj = 0; jj < 2; ++jj)
          acc[i][jj] = __builtin_amdgcn_mfma_f32_16x16x32_bf16(Afr[i], Bfr[jj],
                                                               acc[i][jj], 0, 0, 0);
    }
    // ONE barrier per pair: drains pair pt+1's DMA, publishes the buffer
    if (pt < 14) __syncthreads();
  }
#undef LOADB
#undef GLL

  // Epilogue: bf16 partial stores to g_part[ks][bg][o][l].
  // C/D layout: col = lane&15, row = q*4 + r.
  unsigned short* pb = g_part + (size_t)ks * OUTEL + (size_t)bg * OG * LPIX;
  #pragma unroll
  for (int i = 0; i < 4; ++i) {
    const int og = obase + i * 16 + q * 4;
    #pragma unroll
    for (int jj = 0; jj < 2; ++jj) {
      const int cl = lbase + wv * 32 + jj * 16 + m16;
      #pragma unroll
      for (int r = 0; r < 4; ++r)
        pb[(size_t)(og + r) * LPIX + cl] = f2bf(acc[i][jj][r]);
    }
  }
}

// ---------------------------------------------------------------------------
// Reduce: out = sum_ks bf16(g_part[ks]) + bias. 8 elements per thread.
__global__ __launch_bounds__(256) void reduce_part(
    const float* __restrict__ dkb, float* __restrict__ out) {
  const int t8 = blockIdx.x * 256 + threadIdx.x;   // 0..221183
  const size_t e0 = (size_t)t8 * 8;
  const int row = (int)(e0 / LPIX);                // bg*192 + o (8 els same row)
  const float bias = dkb[row];
  float s[8];
  #pragma unroll
  for (int k = 0; k < 8; ++k) s[k] = bias;
  #pragma unroll
  for (int ks = 0; ks < KSPLIT; ++ks) {
    const uint4 v = *reinterpret_cast<const uint4*>(
        g_part + (size_t)ks * OUTEL + e0);
    const unsigned u[4] = {v.x, v.y, v.z, v.w};
    #pragma unroll
    for (int p = 0; p < 4; ++p) {
      union { unsigned u; float f; } lo, hi;
      lo.u = u[p] << 16;
      hi.u = u[p] & 0xffff0000u;
      s[2 * p]     += lo.f;
      s[2 * p + 1] += hi.f;
    }
  }
  float4 o0, o1;
  o0.x = s[0]; o0.y = s[1]; o0.z = s[2]; o0.w = s[3];
  o1.x = s[4]; o1.y = s[5]; o1.z = s[6]; o1.w = s[7];
  reinterpret_cast<float4*>(out)[t8 * 2]     = o0;
  reinterpret_cast<float4*>(out)[t8 * 2 + 1] = o1;
}

// ---------------------------------------------------------------------------
extern "C" void kernel_launch(void* const* d_in, const int* in_sizes, int n_in,
                              void* d_out, int out_size, void* d_ws, size_t ws_size,
                              hipStream_t stream) {
  const float* x   = (const float*)d_in[0];
  const int*   tg  = (const int*)d_in[1];
  const float* dkw = (const float*)d_in[2];
  const float* dkb = (const float*)d_in[3];
  float* out = (float*)d_out;

  prep<<<dim3(1200), 256, 0, stream>>>(x, tg, dkw);
  gemm_masked<<<dim3(1080), 256, 0, stream>>>();
  reduce_part<<<dim3(OUTEL / 2048), 256, 0, stream>>>(dkb, out);
}